// Round 7
// baseline (90.808 us; speedup 1.0000x reference)
//
#include <hip/hip_runtime.h>

// QSP via Laurent polynomial, one kernel (R17).
// u00(theta) = sum_t gamma_t e^{i(2t-127)theta}; gamma from phis.
// R16 measured: gamma-share (designated wave + LDS handoff) saved ~11us as
// predicted; pk-FMA saved ~nothing -> v_pk_fma_f32 is HALF-RATE on CDNA4
// (FP32 peak 157.3 TF == scalar v_fma_f32 rate; no packed-f32 2x since CDNA2).
// R17: scalar-FMA Horner (same rate, no VGPR-pair movs -- readlane result is
// the one allowed SGPR operand of the inner fma), gamma-share kept, and the
// epilogue sincos(127*theta) moved BEFORE the barrier to overlap the gamma
// wave's serial chain. Issue floor/SIMD: Horner 32.8k + gamma 9.1k + misc
// ~5k ~= 47k cyc ~= 20us.

__device__ __forceinline__ float wave_shr1(float x) {
    // lane L <- lane L-1, lane 0 <- 0 (DPP wave_shr:1, bound_ctrl=1)
    return __builtin_bit_cast(float,
        __builtin_amdgcn_update_dpp(0, __builtin_bit_cast(int, x),
                                    0x138, 0xf, 0xf, true));
}

__device__ __forceinline__ float rlane(float x, int l) {
    // broadcast lane l's value to all lanes (l must be wave-uniform)
    return __builtin_bit_cast(float,
        __builtin_amdgcn_readlane(__builtin_bit_cast(int, x), l));
}

__global__ __launch_bounds__(256, 4) void qsp_fused(
    const float* __restrict__ th,
    const float* __restrict__ phis,
    float* __restrict__ out,    // [0,B): real, [B,2B): imag
    int Bq8)                     // B/8
{
    __shared__ float4 gsh[64];   // lane L -> (g_{2L}.r, g_{2L}.i, g_{2L+1}.r, g_{2L+1}.i)

    const int tid  = threadIdx.x;
    const int lane = tid & 63;
    const int wv   = tid >> 6;
    const int gwv  = blockIdx.x & 3;   // designated gamma wave for this block
    const int idx  = blockIdx.x * blockDim.x + tid;
    const int lidx = (idx < Bq8) ? idx : 0;

    // issue theta loads first; latency hides under gamma/prologue
    const float4 ta = ((const float4*)th)[2 * lidx];
    const float4 tb = ((const float4*)th)[2 * lidx + 1];

    if (wv == gwv) {
        // ---- gamma recurrence (validated R6-R9/R14/R16), this wave only ----
        float sp, cp;
        __sincosf(phis[lane], &sp, &cp);
        const float hAx = 0.5f * cp, hAy = 0.5f * sp;        // k = lane
        __sincosf(phis[lane + 64], &sp, &cp);
        const float hBx = 0.5f * cp, hBy = 0.5f * sp;        // k = lane + 64

        float A0r = 0.f, A0i = 0.f, B0r = 0.f, B0i = 0.f;
        float A1r = 0.f, A1i = 0.f, B1r = 0.f, B1i = 0.f;
        const float h0x = rlane(hAx, 0), h0y = rlane(hAy, 0);
        if (lane == 0) { A0r = 2.f * h0x; A0i = 2.f * h0y; } // A[0] = e_0

        #define QSP_REC(hx_, hy_)                                             \
        {                                                                     \
            const float hx = (hx_), hy = (hy_);                               \
            const float pAr = wave_shr1(A1r), pAi = wave_shr1(A1i);           \
            const float pBr = wave_shr1(B1r), pBi = wave_shr1(B1i);           \
            const float u0r = pAr + pBr, u0i = pAi + pBi;                     \
            const float v0r = A0r - B0r, v0i = A0i - B0i;                     \
            const float sA0r = u0r + v0r, sA0i = u0i + v0i;                   \
            const float sB0r = u0r - v0r, sB0i = u0i - v0i;                   \
            const float u1r = A0r + B0r, u1i = A0i + B0i;                     \
            const float v1r = A1r - B1r, v1i = A1i - B1i;                     \
            const float sA1r = u1r + v1r, sA1i = u1i + v1i;                   \
            const float sB1r = u1r - v1r, sB1i = u1i - v1i;                   \
            A0r = fmaf(hx, sA0r, -hy * sA0i);                                 \
            A0i = fmaf(hx, sA0i,  hy * sA0r);                                 \
            B0r = fmaf(hx, sB0r,  hy * sB0i);                                 \
            B0i = fmaf(hx, sB0i, -hy * sB0r);                                 \
            A1r = fmaf(hx, sA1r, -hy * sA1i);                                 \
            A1i = fmaf(hx, sA1i,  hy * sA1r);                                 \
            B1r = fmaf(hx, sB1r,  hy * sB1i);                                 \
            B1i = fmaf(hx, sB1i, -hy * sB1r);                                 \
        }
        #pragma unroll 4
        for (int k = 1; k < 64; ++k)   QSP_REC(rlane(hAx, k), rlane(hAy, k))
        #pragma unroll 4
        for (int k = 0; k < 64; ++k)   QSP_REC(rlane(hBx, k), rlane(hBy, k))
        #undef QSP_REC

        gsh[lane] = make_float4(A0r, A0i, A1r, A1i);
    }

    // ---- per-thread prologue (all waves; overlaps gamma wave's recurrence) -
    // z = e^{2 i theta}, and the final-rotation factors e^{-127 i theta}
    const float th8[8] = {ta.x, ta.y, ta.z, ta.w, tb.x, tb.y, tb.z, tb.w};
    float zr[8], zi[8], S7[8], C7[8];
    #pragma unroll
    for (int e = 0; e < 8; ++e) {
        float s, c;
        __sincosf(2.f * th8[e], &s, &c);
        zr[e] = c; zi[e] = s;
        __sincosf(127.f * th8[e], &s, &c);
        S7[e] = s; C7[e] = c;
    }

    float ar[8], ai[8];
    #pragma unroll
    for (int e = 0; e < 8; ++e) { ar[e] = 0.f; ai[e] = 0.f; }

    __syncthreads();

    // every wave: lane L fetches gamma pair (2L, 2L+1) into registers
    const float4 g = gsh[lane];
    const float G0r = g.x, G0i = g.y, G1r = g.z, G1i = g.w;

    // ---- Horner in z, t = 127..0; gamma broadcast via readlane -------------
    // readlane result (SGPR) feeds the inner fma addend directly.
    #define QSP_STEP(gr, gi)                                                  \
        _Pragma("unroll")                                                     \
        for (int e = 0; e < 8; ++e) {                                         \
            const float nr = fmaf(ar[e], zr[e], fmaf(-ai[e], zi[e], (gr)));   \
            const float ni = fmaf(ar[e], zi[e], fmaf( ai[e], zr[e], (gi)));   \
            ar[e] = nr; ai[e] = ni;                                           \
        }

    #pragma unroll 2
    for (int jj = 63; jj >= 0; --jj) {
        const float g1r = rlane(G1r, jj), g1i = rlane(G1i, jj);
        QSP_STEP(g1r, g1i)               // t = 2jj+1
        const float g0r = rlane(G0r, jj), g0i = rlane(G0i, jj);
        QSP_STEP(g0r, g0i)               // t = 2jj
    }
    #undef QSP_STEP

    // ---- multiply by e^{-127 i theta}: re = ar*C + ai*S, im = ai*C - ar*S --
    float orv[8], oiv[8];
    #pragma unroll
    for (int e = 0; e < 8; ++e) {
        orv[e] = fmaf(ar[e], C7[e],  ai[e] * S7[e]);
        oiv[e] = fmaf(ai[e], C7[e], -ar[e] * S7[e]);
    }

    if (idx < Bq8) {
        float4* o4 = (float4*)out;
        const int ib = 2 * Bq8;   // imag base in float4 units (= B/4)
        o4[2 * idx]          = make_float4(orv[0], orv[1], orv[2], orv[3]);
        o4[2 * idx + 1]      = make_float4(orv[4], orv[5], orv[6], orv[7]);
        o4[ib + 2 * idx]     = make_float4(oiv[0], oiv[1], oiv[2], oiv[3]);
        o4[ib + 2 * idx + 1] = make_float4(oiv[4], oiv[5], oiv[6], oiv[7]);
    }
}

extern "C" void kernel_launch(void* const* d_in, const int* in_sizes, int n_in,
                              void* d_out, int out_size, void* d_ws, size_t ws_size,
                              hipStream_t stream)
{
    const float* th   = (const float*)d_in[0];
    const float* phis = (const float*)d_in[1];
    float* out = (float*)d_out;
    const int B = in_sizes[0];          // 2097152
    const int Bq8 = B >> 3;             // 262144 threads
    const int block = 256;              // 4 waves
    const int grid = (Bq8 + block - 1) / block;   // 1024 blocks = 4/CU, 16 waves/CU
    qsp_fused<<<grid, block, 0, stream>>>(th, phis, out, Bq8);
}